// Round 1
// 167.115 us; speedup vs baseline: 1.0066x; 1.0066x over previous
//
#include <hip/hip_runtime.h>
#include <hip/hip_bf16.h>

#define MSEQ 2048

typedef __attribute__((ext_vector_type(8))) short short8;
typedef __attribute__((ext_vector_type(4))) short short4v;
typedef __attribute__((ext_vector_type(4))) float f32x4;

static __device__ __forceinline__ short bf16b(float f) {
    __hip_bfloat16 h = __float2bfloat16(f);   // RNE
    return *reinterpret_cast<short*>(&h);
}

// raw 2^x (input is pre-scaled by log2e at the K projection)
static __device__ __forceinline__ float fast_exp2(float x) {
    float r;
    asm("v_exp_f32 %0, %1" : "=v"(r) : "v"(x));
    return r;
}

// async global->LDS, 16B per lane; LDS dest = wave-uniform base + lane*16
static __device__ __forceinline__ void gl_lds16(const void* g, void* l) {
    __builtin_amdgcn_global_load_lds(
        (const __attribute__((address_space(1))) unsigned int*)g,
        (__attribute__((address_space(3))) unsigned int*)l, 16, 0, 0);
}

// ---------------- x fp32 -> bf16 ----------------
__global__ __launch_bounds__(256) void xcvt_kernel(
    const float* __restrict__ x, unsigned short* __restrict__ xb)
{
    const size_t i = ((size_t)blockIdx.x * 256 + threadIdx.x) * 8;
    const float4 a = *(const float4*)(x + i);
    const float4 b = *(const float4*)(x + i + 4);
    short8 o;
    o[0]=bf16b(a.x); o[1]=bf16b(a.y); o[2]=bf16b(a.z); o[3]=bf16b(a.w);
    o[4]=bf16b(b.x); o[5]=bf16b(b.y); o[6]=bf16b(b.z); o[7]=bf16b(b.w);
    *(short8*)(xb + i) = o;
}

// ---------------- W -> WT[n][k] bf16 (n: 0..127 Wq | 128..255 Wk | 256..767 Wv) ----------------
__global__ __launch_bounds__(256) void wtrans_kernel(
    const float* __restrict__ Wq, const float* __restrict__ Wk,
    const float* __restrict__ Wv, unsigned short* __restrict__ WT)
{
    const int nt = blockIdx.x;   // 12 tiles of 64 n
    const int kt = blockIdx.y;   // 8 tiles of 64 k
    const int t  = threadIdx.x;
    const int k0 = kt*64;

    const float* W; int ld, n0;
    if (nt < 2)      { W = Wq; ld = 128; n0 = nt*64; }
    else if (nt < 4) { W = Wk; ld = 128; n0 = (nt-2)*64; }
    else             { W = Wv; ld = 512; n0 = (nt-4)*64; }

    __shared__ unsigned short Ts[64*72];   // [n][k], 144B rows

    #pragma unroll
    for (int s = 0; s < 4; ++s) {
        const int lin = s*256 + t;
        const int krow = lin >> 4, ng = lin & 15;
        const float4 v = *(const float4*)(W + (size_t)(k0+krow)*ld + n0 + ng*4);
        Ts[(ng*4+0)*72 + krow] = (unsigned short)bf16b(v.x);
        Ts[(ng*4+1)*72 + krow] = (unsigned short)bf16b(v.y);
        Ts[(ng*4+2)*72 + krow] = (unsigned short)bf16b(v.z);
        Ts[(ng*4+3)*72 + krow] = (unsigned short)bf16b(v.w);
    }
    __syncthreads();
    #pragma unroll
    for (int s = 0; s < 2; ++s) {
        const int lin = s*256 + t;
        const int nrow = lin >> 3, kg = lin & 7;
        *(short8*)(WT + (size_t)(nt*64 + nrow)*512 + k0 + kg*8) = *(const short8*)&Ts[nrow*72 + kg*8];
    }
}

// ---------------- Fused projection GEMM, bf16 MFMA ----------------
// nt==1 (K) output is pre-scaled by 0.25*log2(e) so attn can use raw v_exp_f32
// (exp(relu(0.25*qk)) == 2^relu(0.25*log2e*qk); relu commutes with the positive scale).
__global__ __launch_bounds__(256, 2) void proj_mfma(
    const unsigned short* __restrict__ xb, const unsigned short* __restrict__ WT,
    const float* __restrict__ bq, const float* __restrict__ bk, const float* __restrict__ bv,
    unsigned short* __restrict__ Qb, unsigned short* __restrict__ Kb, unsigned short* __restrict__ Vt)
{
    const int nt = blockIdx.x;        // 0..5 (0=Q,1=K,2..5=V)
    const int r0 = blockIdx.y * 128;  // m
    const int n0 = nt * 128;
    const int t = threadIdx.x, w = t >> 6, lane = t & 63, l15 = lane & 15, quad = lane >> 4;
    const int qh = w >> 1, chh = w & 1;

    __shared__ short smem[128*136];   // As/Bs alias the front, Ts uses all
    short* As = smem;                 // [128 m][32 k]
    short* Bs = smem + 128*32;        // [128 n][32 k]

    f32x4 acc[4][4];
    #pragma unroll
    for (int i = 0; i < 4; ++i)
        #pragma unroll
        for (int j = 0; j < 4; ++j) acc[i][j] = {0.f,0.f,0.f,0.f};

    const int arow = lane >> 2, akg = lane & 3;

    for (int kk = 0; kk < 512; kk += 32) {
        #pragma unroll
        for (int s = 0; s < 2; ++s) {
            const int row = w*32 + s*16 + arow;
            gl_lds16(xb + (size_t)(r0+row)*512 + kk + akg*8, As + (w*32 + s*16)*32);
            gl_lds16(WT + (size_t)(n0+row)*512 + kk + akg*8, Bs + (w*32 + s*16)*32);
        }
        __syncthreads();
        short8 Af[4], Bf[4];
        #pragma unroll
        for (int i = 0; i < 4; ++i) Af[i] = *(const short8*)&As[(qh*64 + i*16 + l15)*32 + quad*8];
        #pragma unroll
        for (int j = 0; j < 4; ++j) Bf[j] = *(const short8*)&Bs[(chh*64 + j*16 + l15)*32 + quad*8];
        #pragma unroll
        for (int i = 0; i < 4; ++i)
            #pragma unroll
            for (int j = 0; j < 4; ++j)
                acc[i][j] = __builtin_amdgcn_mfma_f32_16x16x32_bf16(Af[i], Bf[j], acc[i][j], 0, 0, 0);
        __syncthreads();
    }

    const float* bias = (nt == 0) ? bq : (nt == 1) ? bk : (bv + (nt-2)*128);
    const float kscale = (nt == 1) ? 0.36067376022224085f : 1.0f;  // 0.25 * log2(e)
    float bj[4];
    #pragma unroll
    for (int j = 0; j < 4; ++j) bj[j] = bias[chh*64 + j*16 + l15];

    short* Ts = smem;   // [128][136]
    if (nt < 2) {       // row-major [m][n]
        #pragma unroll
        for (int i = 0; i < 4; ++i)
            #pragma unroll
            for (int j = 0; j < 4; ++j)
                #pragma unroll
                for (int r = 0; r < 4; ++r)
                    Ts[(qh*64 + i*16 + quad*4 + r)*136 + chh*64 + j*16 + l15] =
                        bf16b((acc[i][j][r] + bj[j]) * kscale);
    } else {            // transposed [n][m] = [ch][key]
        #pragma unroll
        for (int i = 0; i < 4; ++i)
            #pragma unroll
            for (int j = 0; j < 4; ++j)
                #pragma unroll
                for (int r = 0; r < 4; ++r)
                    Ts[(chh*64 + j*16 + l15)*136 + qh*64 + i*16 + quad*4 + r] =
                        bf16b(acc[i][j][r] + bj[j]);
    }
    __syncthreads();

    if (nt < 2) {
        unsigned short* Out = (nt == 0) ? Qb : Kb;
        #pragma unroll
        for (int s = 0; s < 8; ++s) {
            const int lin = s*256 + t, row = lin >> 4, seg = lin & 15;
            *(short8*)(Out + (size_t)(r0+row)*128 + seg*8) = *(const short8*)&Ts[row*136 + seg*8];
        }
    } else {
        const int b = r0 >> 11, key0 = r0 & 2047, chBase = (nt-2)*128;
        #pragma unroll
        for (int s = 0; s < 8; ++s) {
            const int lin = s*256 + t, row = lin >> 4, seg = lin & 15;
            *(short8*)(Vt + ((size_t)(b*512 + chBase + row))*MSEQ + key0 + seg*8) =
                *(const short8*)&Ts[row*136 + seg*8];
        }
    }
}

// ---------------- Fused masked attention, bf16 MFMA, S^T score layout ----------------
// q-tile = 32 rows (grid.y = 64): LDS 19.3KB -> 8 blocks/CU, occupancy 2x.
// wsum cross-lane reduction moved OUT of the kt loop (was 256 shuffles/wave, now 4).
// K pre-scaled by 0.25*log2e at projection -> inner loop is max/exp2/mul/cvt only.
__global__ __launch_bounds__(256, 8) void attn_mfma(
    const unsigned short* __restrict__ Qb, const unsigned short* __restrict__ Kb,
    const unsigned short* __restrict__ Vt, const int* __restrict__ mask,
    const float* __restrict__ gamma, float* __restrict__ out)
{
    const int bh = blockIdx.x;       // 32
    const int b  = bh >> 3, h = bh & 7;
    const int m0 = blockIdx.y * 32;  // 64 q-tiles of 32
    const int t  = threadIdx.x;
    const int wave = t >> 6, lane = t & 63, l15 = lane & 15, quad = lane >> 4;

    __shared__ short Ks[64*24];      // [key][24]; shorts 16..23 stay 0 (K=16 padded to 32)
    __shared__ short Qs[32*24];      // [q][24];   same zero-pad trick
    __shared__ short VtS[64*72];     // [ch][key]
    __shared__ short Ws[32*72];      // [q][key]
    __shared__ float msk[64];
    __shared__ float wsl[4*32];      // per-wave wsum partials
    __shared__ float wsums[32];

    // zero the k-pad of Ks and Qs once; stage Q tile once
    {
        short8 z = {0,0,0,0,0,0,0,0};
        if (t < 64) *(short8*)&Ks[t*24 + 16] = z;
        if (t < 32) *(short8*)&Qs[t*24 + 16] = z;
    }
    if (t < 64) {
        const int row = t >> 1, half = t & 1;
        *(short8*)&Qs[row*24 + half*8] =
            *(const short8*)(Qb + (size_t)(b*MSEQ + m0 + row)*128 + h*16 + half*8);
    }
    __syncthreads();

    const int kso = (quad < 2) ? quad*8 : 16;   // quads 2/3 read the zero pad (d>=16)
    short8 qfrag[2];
    #pragma unroll
    for (int c = 0; c < 2; ++c)
        qfrag[c] = *(const short8*)&Qs[(c*16 + l15)*24 + kso];

    f32x4 acc[2] = {{0.f,0.f,0.f,0.f},{0.f,0.f,0.f,0.f}};
    float wsum_acc[2] = {0.f,0.f};
    const int qh = wave >> 1, chh = wave & 1;

    for (int kt = 0; kt < 32; ++kt) {
        const int kn0 = kt*64;
        if (t < 128) {
            const int key = t >> 1, half = t & 1;
            *(short8*)&Ks[key*24 + half*8] =
                *(const short8*)(Kb + (size_t)(b*MSEQ + kn0 + key)*128 + h*16 + half*8);
        }
        #pragma unroll
        for (int i = 0; i < 2; ++i) {
            const int idx = i*256 + t;
            const int kg = idx & 7, ch = idx >> 3;
            *(short8*)&VtS[ch*72 + kg*8] =
                *(const short8*)(Vt + ((size_t)(b*512 + h*64 + ch))*MSEQ + kn0 + kg*8);
        }
        if (t < 64) msk[t] = (float)mask[b*MSEQ + kn0 + t];
        __syncthreads();

        // ---- scores S^T: wave covers keys wave*16..+15, all 32 q via c-loop ----
        const short8 kfrag = *(const short8*)&Ks[(wave*16 + l15)*24 + kso];  // A[m=key=l15][k=d]
        const float4 mk4 = *(const float4*)&msk[wave*16 + quad*4];           // keys quad*4..+3
        #pragma unroll
        for (int c = 0; c < 2; ++c) {
            f32x4 s = {0.f,0.f,0.f,0.f};
            s = __builtin_amdgcn_mfma_f32_16x16x32_bf16(kfrag, qfrag[c], s, 0, 0, 0);
            // lane holds q = c*16+l15, keys = wave*16 + quad*4 + r
            // K was pre-scaled by 0.25*log2e -> w = mask * 2^max(s,0)
            float w0 = mk4.x * fast_exp2(fmaxf(s[0], 0.f));
            float w1 = mk4.y * fast_exp2(fmaxf(s[1], 0.f));
            float w2 = mk4.z * fast_exp2(fmaxf(s[2], 0.f));
            float w3 = mk4.w * fast_exp2(fmaxf(s[3], 0.f));
            short4v ws4;
            ws4[0]=bf16b(w0); ws4[1]=bf16b(w1); ws4[2]=bf16b(w2); ws4[3]=bf16b(w3);
            *(short4v*)&Ws[(c*16 + l15)*72 + wave*16 + quad*4] = ws4;   // b64 write
            wsum_acc[c] += (w0 + w1) + (w2 + w3);   // lane-private; reduce after loop
        }
        __syncthreads();

        // ---- PV: wave -> q-rows qh*16..+15, chs chh*32..+31 ----
        short8 Af[2], Bf[2][2];
        #pragma unroll
        for (int kh = 0; kh < 2; ++kh)
            Af[kh] = *(const short8*)&Ws[(qh*16 + l15)*72 + kh*32 + quad*8];
        #pragma unroll
        for (int ci = 0; ci < 2; ++ci)
            #pragma unroll
            for (int kh = 0; kh < 2; ++kh)
                Bf[ci][kh] = *(const short8*)&VtS[((chh*2+ci)*16 + l15)*72 + kh*32 + quad*8];
        #pragma unroll
        for (int ci = 0; ci < 2; ++ci)
            #pragma unroll
            for (int kh = 0; kh < 2; ++kh)
                acc[ci] = __builtin_amdgcn_mfma_f32_16x16x32_bf16(
                    Af[kh], Bf[ci][kh], acc[ci], 0, 0, 0);
        __syncthreads();
    }

    // ---- wsum: quad-group reduce once (4 shuffles/wave total), then cross-wave ----
    #pragma unroll
    for (int c = 0; c < 2; ++c) {
        float r = wsum_acc[c];
        r += __shfl_xor(r, 16, 64);
        r += __shfl_xor(r, 32, 64);
        if (quad == 0) wsl[wave*32 + c*16 + l15] = r;
    }
    __syncthreads();
    if (t < 32) wsums[t] = (wsl[t] + wsl[32+t]) + (wsl[64+t] + wsl[96+t]);
    __syncthreads();

    const float g = gamma[0];
    #pragma unroll
    for (int r = 0; r < 4; ++r) {
        const int row = qh*16 + quad*4 + r;
        const float inv = g / fmaxf(wsums[row], 1e-20f);
        #pragma unroll
        for (int ci = 0; ci < 2; ++ci) {
            const int col = chh*32 + ci*16 + l15;
            out[(size_t)(b*MSEQ + m0 + row)*512 + h*64 + col] = acc[ci][r] * inv;
        }
    }
}

extern "C" void kernel_launch(void* const* d_in, const int* in_sizes, int n_in,
                              void* d_out, int out_size, void* d_ws, size_t ws_size,
                              hipStream_t stream) {
    const float* x     = (const float*)d_in[0];
    const int*   mask  = (const int*)  d_in[1];
    const float* Wq    = (const float*)d_in[2];
    const float* bq    = (const float*)d_in[3];
    const float* Wk    = (const float*)d_in[4];
    const float* bk    = (const float*)d_in[5];
    const float* Wv    = (const float*)d_in[6];
    const float* bv    = (const float*)d_in[7];
    const float* gamma = (const float*)d_in[8];
    float* outp = (float*)d_out;

    // ws (bf16 shorts): xb 8MB | WT 0.75MB | Qb 2MB | Kb 2MB | Vt 8MB
    unsigned short* xb = (unsigned short*)d_ws;
    unsigned short* WT = xb + (size_t)8192*512;
    unsigned short* Qb = WT + (size_t)768*512;
    unsigned short* Kb = Qb + (size_t)8192*128;
    unsigned short* Vt = Kb + (size_t)8192*128;

    xcvt_kernel<<<2048, 256, 0, stream>>>(x, xb);
    wtrans_kernel<<<dim3(12, 8), 256, 0, stream>>>(Wq, Wk, Wv, WT);
    proj_mfma<<<dim3(6, 64), 256, 0, stream>>>(xb, WT, bq, bk, bv, Qb, Kb, Vt);
    attn_mfma<<<dim3(32, 64), 256, 0, stream>>>(Qb, Kb, Vt, mask, gamma, outp);
}